// Round 2
// baseline (197.291 us; speedup 1.0000x reference)
//
#include <hip/hip_runtime.h>

// Morphological dilation2d, MI355X (gfx950).
// out[b,o,h,w] = max_{c,i,j} ( x_zpad[b,c,h+i-2,w+j-2] + weight[o,c,i,j] )
// B=4, C=4, O=4, H=W=1024, K=5, PAD=2, fp32. VALU-bound: floor ~100 instr/output.

constexpr int Himg = 1024, Wimg = 1024, Cin = 4, Cout = 4, Kn = 5;
constexpr int TH = 16, TW = 128;     // output tile per 256-thread block (8 px/thread)
constexpr int LR = TH + 4;           // 20 staged rows per channel
constexpr int LCU = TW + 12;         // 140 used cols (halo -4 .. +7 around tile)
constexpr int LC = 164;              // row stride: 164 % 32 == 4 -> staggered banks
constexpr int NCH = LR * (LCU / 4);  // 700 float4 chunks per channel stage

typedef float v2f __attribute__((ext_vector_type(2)));
// constant address space -> uniform loads become s_load (SGPR-resident weights)
typedef const float __attribute__((address_space(4))) cfloat;

// weight [o][c][i][j] -> wt2[((c*5+i)*4+o)*5+j] as duplicated pair {w,w}
__global__ void reorg_w(const float* __restrict__ w, float* __restrict__ wt2) {
  int idx = threadIdx.x;
  if (idx < Cout * Cin * Kn * Kn) {
    int o  = idx / (Cin * Kn * Kn);
    int r  = idx % (Cin * Kn * Kn);
    int c  = r / (Kn * Kn);
    int r2 = r % (Kn * Kn);
    int i  = r2 / Kn, j = r2 % Kn;
    float v = w[idx];
    int dst = (((c * Kn + i) * Cout + o) * Kn + j) * 2;
    wt2[dst + 0] = v;
    wt2[dst + 1] = v;
  }
}

template <bool FAST>
__global__ __launch_bounds__(256) void morph(const float* __restrict__ x,
                                             const float* __restrict__ wt2,
                                             const float* __restrict__ wraw,
                                             float* __restrict__ out) {
  __shared__ __align__(16) float xs[2][LR][LC];
  const int tid = threadIdx.x;
  const int bw = blockIdx.x * TW;
  const int br = blockIdx.y * TH;
  const int b  = blockIdx.z;
  const int tx = tid & 15;   // 16 col-groups x 8 px
  const int ty = tid >> 4;   // 16 rows

  // precomputed staging coordinates (tid-only, hoisted out of the c-loop)
  int rowk[3], gck[3];
  bool act[3];
#pragma unroll
  for (int k = 0; k < 3; ++k) {
    int idx = tid + k * 256;
    act[k] = idx < NCH;
    int row = idx / 35;
    int ch  = idx - row * 35;
    rowk[k] = row;
    gck[k]  = bw - 4 + ch * 4;
  }
  const bool interior = (bw > 0) && (bw < Wimg - TW) && (br > 0) && (br < Himg - TH);

  float4 pre[3];
  auto ld = [&](int c) {
#pragma unroll
    for (int k = 0; k < 3; ++k) {
      float4 v = make_float4(0.f, 0.f, 0.f, 0.f);
      if (act[k]) {
        const int gr = br - 2 + rowk[k];
        const int gc = gck[k];
        const float* src = x + ((size_t)(b * Cin + c) * Himg + gr) * Wimg;
        if (interior) {
          v = *(const float4*)(src + gc);
        } else if ((unsigned)gr < (unsigned)Himg) {
          if (gc >= 0 && gc <= Wimg - 4) {
            v = *(const float4*)(src + gc);
          } else {
            if ((unsigned)(gc + 0) < (unsigned)Wimg) v.x = src[gc + 0];
            if ((unsigned)(gc + 1) < (unsigned)Wimg) v.y = src[gc + 1];
            if ((unsigned)(gc + 2) < (unsigned)Wimg) v.z = src[gc + 2];
            if ((unsigned)(gc + 3) < (unsigned)Wimg) v.w = src[gc + 3];
          }
        }
      }
      pre[k] = v;
    }
  };
  auto st = [&](int buf) {
#pragma unroll
    for (int k = 0; k < 3; ++k) {
      if (act[k]) *(float4*)&xs[buf][rowk[k]][(gck[k] - (bw - 4))] = pre[k];
    }
  };

  v2f acc[Cout][4];
#pragma unroll
  for (int o = 0; o < Cout; ++o)
#pragma unroll
    for (int m = 0; m < 4; ++m) acc[o][m] = (v2f){-3.4e38f, -3.4e38f};

  cfloat* cw = (cfloat*)wt2;

  ld(0);
  st(0);
  __syncthreads();

#pragma unroll 1
  for (int c = 0; c < Cin; ++c) {
    const int buf = c & 1;
    if (c < Cin - 1) ld(c + 1);   // global loads in flight during compute

#pragma unroll
    for (int i = 0; i < Kn; ++i) {
      const float* rowp = &xs[buf][ty + i][tx * 8];
      // stride-4 data pairs: D[s] = {win[s+2], win[s+6]} -> outputs (m, m+4)
      v2f D[9];
#pragma unroll
      for (int s = 0; s < 9; ++s) {
        v2f d; d.x = rowp[s + 2]; d.y = rowp[s + 6];
        D[s] = d;
      }
#pragma unroll
      for (int o = 0; o < Cout; ++o) {
        v2f wv[Kn];
#pragma unroll
        for (int j = 0; j < Kn; ++j) {
          if (FAST) {
            const int widx = ((((c * Kn + i) * Cout + o) * Kn) + j) * 2;
            v2f w2; w2.x = cw[widx]; w2.y = cw[widx + 1];
            wv[j] = w2;
          } else {
            const float s0 = wraw[((o * Cin + c) * Kn + i) * Kn + j];
            v2f w2; w2.x = s0; w2.y = s0;
            wv[j] = w2;
          }
        }
#pragma unroll
        for (int m = 0; m < 4; ++m) {
          v2f v0 = D[m + 0] + wv[0];
          v2f v1 = D[m + 1] + wv[1];
          v2f v2_ = D[m + 2] + wv[2];
          v2f v3 = D[m + 3] + wv[3];
          v2f v4 = D[m + 4] + wv[4];
          v2f a = acc[o][m], t1, t2;
          t1.x = fmaxf(fmaxf(v0.x, v1.x), v2_.x);   // v_max3_f32
          t1.y = fmaxf(fmaxf(v0.y, v1.y), v2_.y);
          t2.x = fmaxf(fmaxf(v3.x, v4.x), a.x);
          t2.y = fmaxf(fmaxf(v3.y, v4.y), a.y);
          a.x = fmaxf(t1.x, t2.x);
          a.y = fmaxf(t1.y, t2.y);
          acc[o][m] = a;
        }
      }
    }
    if (c < Cin - 1) st(buf ^ 1);
    __syncthreads();
  }

  // epilogue: two float4 stores per output channel
  const int h = br + ty;
#pragma unroll
  for (int o = 0; o < Cout; ++o) {
    const size_t obase = ((size_t)(b * Cout + o) * Himg + h) * Wimg + bw + tx * 8;
    float4 lo = make_float4(acc[o][0].x, acc[o][1].x, acc[o][2].x, acc[o][3].x);
    float4 hi = make_float4(acc[o][0].y, acc[o][1].y, acc[o][2].y, acc[o][3].y);
    *(float4*)&out[obase + 0] = lo;
    *(float4*)&out[obase + 4] = hi;
  }
}

extern "C" void kernel_launch(void* const* d_in, const int* in_sizes, int n_in,
                              void* d_out, int out_size, void* d_ws, size_t ws_size,
                              hipStream_t stream) {
  const float* x = (const float*)d_in[0];
  const float* w = (const float*)d_in[1];
  float* out = (float*)d_out;

  dim3 grid(Wimg / TW, Himg / TH, 4);  // (8, 64, 4)

  if (ws_size >= sizeof(float) * 2 * Cout * Cin * Kn * Kn) {
    float* wt2 = (float*)d_ws;
    reorg_w<<<dim3(1), dim3(512), 0, stream>>>(w, wt2);
    morph<true><<<grid, dim3(256), 0, stream>>>(x, wt2, w, out);
  } else {
    morph<false><<<grid, dim3(256), 0, stream>>>(x, nullptr, w, out);
  }
}

// Round 3
// 184.549 us; speedup vs baseline: 1.0690x; 1.0690x over previous
//
#include <hip/hip_runtime.h>

// Morphological dilation2d, MI355X (gfx950), fp32.
// out[b,o,h,w] = max_{c,i,j} ( x_zpad[b,c,h+i-2,w+j-2] + w[o,c,i,j] )
// B=4, C=4, O=4, H=W=1024, K=5, PAD=2.
//
// R3 design: VALU floor ~100 instr/elem (50 pk_add + 50 max3).
//  - block: 128W x 64H x 2 output channels; thread: 8W x 4H x 2o = 64 elems
//  - LDS: one channel staged at a time, 68 rows x stride 140 (16B-aligned rows,
//    4-float rotation every 4 rows -> balanced banks for b128 reads)
//  - window read: 4 x ds_read_b128 per input row; even pk pairs = free
//    sub-pairs of quads; 5 odd pairs built with v_movs
//  - weights: addrspace(4) uniform s_loads, broadcast into pk operands

constexpr int Himg = 1024, Wimg = 1024, Cin = 4, Cout = 4, Kn = 5;
constexpr int TW = 128, THt = 64;   // block tile
constexpr int SR = 68;              // staged rows = 64 + 4 halo
constexpr int SC4 = 34;             // 136 staged cols (bw-4 .. bw+131) / 4
constexpr int S = 140;              // LDS row stride in floats
constexpr int NCHUNK = SR * SC4;    // 2312 float4 chunks per channel

typedef float v2f __attribute__((ext_vector_type(2)));
typedef const float __attribute__((address_space(4))) cfloat;

__device__ __forceinline__ int rot(int r) { return ((r >> 2) & 1) * 4; }

__global__ __launch_bounds__(256, 4) void morph(const float* __restrict__ x,
                                                const float* __restrict__ w,
                                                float* __restrict__ out) {
  __shared__ __align__(16) float xs[SR * S];  // 38080 B -> 4 blocks/CU
  const int tid = threadIdx.x;
  const int bw = blockIdx.x * TW;
  const int br = blockIdx.y * THt;
  const int b  = blockIdx.z >> 1;
  const int o0 = (blockIdx.z & 1) * 2;
  const int tx = tid & 15;
  const int ty = tid >> 4;
  const int h0 = ty * 4;   // first output row within tile
  const int w0 = tx * 8;   // first output col within tile

  cfloat* cw = (cfloat*)w;  // uniform indices -> s_load

  v2f acc[2][4][4];  // [oo][d][m] ; pair = pixels (w0+2m, w0+2m+1)
#pragma unroll
  for (int oo = 0; oo < 2; ++oo)
#pragma unroll
    for (int d = 0; d < 4; ++d)
#pragma unroll
      for (int m = 0; m < 4; ++m) acc[oo][d][m] = (v2f){-3.4e38f, -3.4e38f};

#pragma unroll 1
  for (int c = 0; c < Cin; ++c) {
    if (c) __syncthreads();
    // ---- stage channel c: rows br-2..br+65, cols bw-4..bw+131 (zero pad) ----
    for (int idx = tid; idx < NCHUNK; idx += 256) {
      const int row = idx / SC4;
      const int ch  = idx - row * SC4;
      const int gr  = br - 2 + row;
      const int gc  = bw - 4 + ch * 4;
      float4 v = make_float4(0.f, 0.f, 0.f, 0.f);
      if ((unsigned)gr < (unsigned)Himg) {
        const float* src = x + ((size_t)(b * Cin + c) * Himg + gr) * Wimg;
        if (gc >= 0 && gc <= Wimg - 4) {
          v = *(const float4*)(src + gc);
        } else {
          if ((unsigned)(gc + 0) < (unsigned)Wimg) v.x = src[gc + 0];
          if ((unsigned)(gc + 1) < (unsigned)Wimg) v.y = src[gc + 1];
          if ((unsigned)(gc + 2) < (unsigned)Wimg) v.z = src[gc + 2];
          if ((unsigned)(gc + 3) < (unsigned)Wimg) v.w = src[gc + 3];
        }
      }
      *(float4*)&xs[row * S + rot(row) + ch * 4] = v;
    }
    __syncthreads();

    // ---- compute: thread's 8 input rows feed its 4 output rows ----
#pragma unroll 1
    for (int rr = 0; rr < 8; ++rr) {
      const int lrow = h0 + rr;  // staged row index (global row br-2+h0+rr)
      const float* rb = &xs[lrow * S + rot(lrow) + w0];  // L[t] = rb[t], t=0..15
      const float4 q0 = *(const float4*)(rb + 0);
      const float4 q1 = *(const float4*)(rb + 4);
      const float4 q2 = *(const float4*)(rb + 8);
      const float4 q3 = *(const float4*)(rb + 12);
      // even pairs E[e] = {L[2e+2], L[2e+3]}  (free sub-pairs of quads)
      v2f E[6];
      E[0] = (v2f){q0.z, q0.w};
      E[1] = (v2f){q1.x, q1.y};
      E[2] = (v2f){q1.z, q1.w};
      E[3] = (v2f){q2.x, q2.y};
      E[4] = (v2f){q2.z, q2.w};
      E[5] = (v2f){q3.x, q3.y};
      // odd pairs O[k] = {L[2k+3], L[2k+4]}  (cross-quad, v_movs)
      v2f O[5];
      O[0] = (v2f){q0.w, q1.x};
      O[1] = (v2f){q1.y, q1.z};
      O[2] = (v2f){q1.w, q2.x};
      O[3] = (v2f){q2.y, q2.z};
      O[4] = (v2f){q2.w, q3.x};

#pragma unroll
      for (int oo = 0; oo < 2; ++oo) {
#pragma unroll
        for (int d = 0; d < 4; ++d) {
          const int i = rr - d;            // kernel row index
          if (i >= 0 && i < Kn) {          // wave-uniform branch
            const int wb = (((o0 + oo) * Cin + c) * Kn + i) * Kn;
            const float w_0 = cw[wb + 0];
            const float w_1 = cw[wb + 1];
            const float w_2 = cw[wb + 2];
            const float w_3 = cw[wb + 3];
            const float w_4 = cw[wb + 4];
            const v2f W0 = (v2f){w_0, w_0};
            const v2f W1 = (v2f){w_1, w_1};
            const v2f W2 = (v2f){w_2, w_2};
            const v2f W3 = (v2f){w_3, w_3};
            const v2f W4 = (v2f){w_4, w_4};
#pragma unroll
            for (int m = 0; m < 4; ++m) {
              // term j for pixel pair m: pair start 2m+j+2
              v2f s0 = E[m + 0] + W0;  // j=0
              v2f s1 = O[m + 0] + W1;  // j=1
              v2f s2 = E[m + 1] + W2;  // j=2
              v2f s3 = O[m + 1] + W3;  // j=3
              v2f s4 = E[m + 2] + W4;  // j=4
              v2f a = acc[oo][d][m];
              a.x = fmaxf(fmaxf(fmaxf(s0.x, s1.x), s2.x),
                          fmaxf(fmaxf(s3.x, s4.x), a.x));   // 2x max3 + max
              a.y = fmaxf(fmaxf(fmaxf(s0.y, s1.y), s2.y),
                          fmaxf(fmaxf(s3.y, s4.y), a.y));
              acc[oo][d][m] = a;
            }
          }
        }
      }
    }
  }

  // ---- epilogue: 16 coalesced float4 stores ----
#pragma unroll
  for (int oo = 0; oo < 2; ++oo) {
#pragma unroll
    for (int d = 0; d < 4; ++d) {
      const int h = br + h0 + d;
      const size_t base =
          ((size_t)(b * Cout + o0 + oo) * Himg + h) * Wimg + bw + w0;
      *(float4*)&out[base + 0] =
          make_float4(acc[oo][d][0].x, acc[oo][d][0].y, acc[oo][d][1].x, acc[oo][d][1].y);
      *(float4*)&out[base + 4] =
          make_float4(acc[oo][d][2].x, acc[oo][d][2].y, acc[oo][d][3].x, acc[oo][d][3].y);
    }
  }
}

extern "C" void kernel_launch(void* const* d_in, const int* in_sizes, int n_in,
                              void* d_out, int out_size, void* d_ws, size_t ws_size,
                              hipStream_t stream) {
  const float* x = (const float*)d_in[0];
  const float* w = (const float*)d_in[1];
  float* out = (float*)d_out;

  dim3 grid(Wimg / TW, Himg / THt, 4 * 2);  // (8, 16, 8) = 1024 blocks, 4/CU
  morph<<<grid, dim3(256), 0, stream>>>(x, w, out);
}